// Round 5
// baseline (1827.978 us; speedup 1.0000x reference)
//
#include <hip/hip_runtime.h>

#define H  1024
#define V  512
#define WV 300
#define S  64
#define N  512

#define KP 8     // split-K parts
#define KC 64    // K chunk staged in LDS

// ---- workspace float offsets ----
#define WS_HALL   0                         // [S,H]
#define WS_CAT    (S*H)                     // [S,1536]  (hat | ac)
#define WS_W2V    (WS_CAT + S*1536)         // [S,H]
#define WS_CHOICE (WS_W2V + S*H)            // [S,2]
#define WS_SCAL   (WS_CHOICE + 2*S)         // [S]
#define WS_ACSUM  (WS_SCAL + S)             // [S]
#define WS_KT     (WS_ACSUM + S)            // [S,H]
#define WS_ATT    (WS_KT + S*H)             // [S,N]
#define WS_SLOTP  (WS_ATT + S*N)            // [2][64][1024] partial bar_et
#define WS_SLOTA  (WS_SLOTP + 2*64*1024)    // [2][64] partial asum
#define WS_FLAGS  (WS_SLOTA + 2*64)         // [64] monotonic arrival flags

// ---- out float offsets ----
#define OUT_EP   0                  // [S,N]
#define OUT_AC   (S*N)              // [S,V]
#define OUT_SE   (S*N + S*V)        // [S,H]
#define OUT_ALL  (OUT_SE + S*H)     // [S,N,H]
#define OUT_ACT  (OUT_ALL + (size_t)S*N*H) // [S,WV]

__device__ __forceinline__ float dot4(float4 a, float4 b) {
  return a.x*b.x + a.y*b.y + a.z*b.z + a.w*b.w;
}

// ---------------------------------------------------------------------------
// Split-K tiled NT GEMM partial: P[mat][kp][64][Ntot-slice] = X[:,kslice] @ W^T
// ---------------------------------------------------------------------------
struct SKArgs {
  const float* X; const float* W0; const float* W1;
  float* pbuf;
  int ldx, K, KS, Ntot;
};

__global__ __launch_bounds__(256) void g_split(SKArgs a) {
  __shared__ float Xs[64][KC + 4];
  __shared__ float Ws[64][KC + 4];
  const int tid = threadIdx.x;
  const int jt = blockIdx.x, kp = blockIdx.y, mat = blockIdx.z;
  const float* W = mat ? a.W1 : a.W0;
  const int jbase = jt * 64, kbase = kp * a.KS;
  const int tm = tid >> 5, tn = tid & 31;
  float acc[8][2];
#pragma unroll
  for (int i = 0; i < 8; ++i) acc[i][0] = acc[i][1] = 0.f;
  const int lr = tid >> 2;
  const int lc = (tid & 3) * 16;
  const float* xrow = a.X + (size_t)lr * a.ldx + kbase + lc;
  const float* wrow = W + (size_t)(jbase + lr) * a.K + kbase + lc;
  float4 xv0, xv1, xv2, xv3, wv0, wv1, wv2, wv3;
  xv0 = ((const float4*)xrow)[0]; xv1 = ((const float4*)xrow)[1];
  xv2 = ((const float4*)xrow)[2]; xv3 = ((const float4*)xrow)[3];
  wv0 = ((const float4*)wrow)[0]; wv1 = ((const float4*)wrow)[1];
  wv2 = ((const float4*)wrow)[2]; wv3 = ((const float4*)wrow)[3];
  for (int k0 = 0; k0 < a.KS; k0 += KC) {
    __syncthreads();
    *(float4*)&Xs[lr][lc +  0] = xv0; *(float4*)&Xs[lr][lc +  4] = xv1;
    *(float4*)&Xs[lr][lc +  8] = xv2; *(float4*)&Xs[lr][lc + 12] = xv3;
    *(float4*)&Ws[lr][lc +  0] = wv0; *(float4*)&Ws[lr][lc +  4] = wv1;
    *(float4*)&Ws[lr][lc +  8] = wv2; *(float4*)&Ws[lr][lc + 12] = wv3;
    __syncthreads();
    if (k0 + KC < a.KS) {
      const float* xp = xrow + k0 + KC;
      const float* wp = wrow + k0 + KC;
      xv0 = ((const float4*)xp)[0]; xv1 = ((const float4*)xp)[1];
      xv2 = ((const float4*)xp)[2]; xv3 = ((const float4*)xp)[3];
      wv0 = ((const float4*)wp)[0]; wv1 = ((const float4*)wp)[1];
      wv2 = ((const float4*)wp)[2]; wv3 = ((const float4*)wp)[3];
    }
#pragma unroll
    for (int kk = 0; kk < KC; kk += 4) {
      float4 w0 = *(const float4*)&Ws[tn][kk];
      float4 w1 = *(const float4*)&Ws[tn + 32][kk];
#pragma unroll
      for (int i = 0; i < 8; ++i) {
        float4 x = *(const float4*)&Xs[tm * 8 + i][kk];
        acc[i][0] += dot4(x, w0);
        acc[i][1] += dot4(x, w1);
      }
    }
  }
  float* base = a.pbuf + ((size_t)(mat * KP + kp) * 64) * a.Ntot + jbase;
#pragma unroll
  for (int i = 0; i < 8; ++i) {
    const int r = tm * 8 + i;
    base[(size_t)r * a.Ntot + tn]      = acc[i][0];
    base[(size_t)r * a.Ntot + tn + 32] = acc[i][1];
  }
}

// Epilogue: sum KP partials + bias + activation, scatter to 1-2 outputs.
struct EPArgs {
  const float* pbuf;
  const float* B0; const float* B1;
  float* o1_0; float* o2_0; float* o1_1; float* o2_1;
  int nsh, ld1_0, ld2_0, ld1_1, ld2_1, act;
};

__global__ __launch_bounds__(256) void ep_k(EPArgs e) {
  const int mat = blockIdx.y;
  const int Ntot = 1 << e.nsh;
  const int idx = blockIdx.x * 256 + threadIdx.x;
  const int r = idx >> e.nsh, j = idx & (Ntot - 1);
  const float* pb = e.pbuf + (size_t)mat * KP * 64 * Ntot;
  float s = 0.f;
#pragma unroll
  for (int kp = 0; kp < KP; ++kp) s += pb[(size_t)(kp * 64 + r) * Ntot + j];
  s += (mat ? e.B1 : e.B0)[j];
  if (e.act == 1) s = fmaxf(s, 0.f);
  else if (e.act == 2) s = 1.f / (1.f + __expf(-s));
  float* o1 = mat ? e.o1_1 : e.o1_0;
  float* o2 = mat ? e.o2_1 : e.o2_0;
  const int ld1 = mat ? e.ld1_1 : e.ld1_0;
  const int ld2 = mat ? e.ld2_1 : e.ld2_0;
  o1[(size_t)r * ld1 + j] = s;
  if (o2) o2[(size_t)r * ld2 + j] = s;
}

// choice softmax (c0,c1) and acsum. hat read from cat (stride 1536).
__global__ void k_choice(const float* __restrict__ cat, const float* __restrict__ out_ac,
                         const float* __restrict__ W3w, const float* __restrict__ W3b,
                         float* __restrict__ ws) {
  int t = blockIdx.x, tid = threadIdx.x;
  const float* hat = cat + (size_t)t * 1536;
  float4 h4 = *(const float4*)(hat + tid * 4);
  float p[4];
#pragma unroll
  for (int r = 0; r < 3; ++r) {
    float4 w4 = *(const float4*)(W3w + (size_t)r * H + tid * 4);
    p[r] = dot4(h4, w4);
  }
  const float* ac = out_ac + (size_t)t * V;
  p[3] = ac[tid * 2] + ac[tid * 2 + 1];
  __shared__ float red[4][256];
#pragma unroll
  for (int q = 0; q < 4; ++q) red[q][tid] = p[q];
  __syncthreads();
  for (int sft = 128; sft > 0; sft >>= 1) {
    if (tid < sft) {
#pragma unroll
      for (int q = 0; q < 4; ++q) red[q][tid] += red[q][tid + sft];
    }
    __syncthreads();
  }
  if (tid == 0) {
    float l0 = red[0][0] + W3b[0], l1 = red[1][0] + W3b[1], l2 = red[2][0] + W3b[2];
    float m  = fmaxf(l0, fmaxf(l1, l2));
    float e0 = __expf(l0 - m), e1 = __expf(l1 - m), e2 = __expf(l2 - m);
    float inv = 1.f / (e0 + e1 + e2);
    ws[WS_CHOICE + t * 2]     = e0 * inv;
    ws[WS_CHOICE + t * 2 + 1] = e1 * inv;
    ws[WS_ACSUM + t]          = red[3][0];
  }
}

// bar_ft = (ac/acsum)@emb -> out_act, plus scal = bar_ft@W4w + W4b (folded).
__global__ __launch_bounds__(256) void k_barft(
    const float* __restrict__ out_ac, const float* __restrict__ emb,
    const float* __restrict__ ws_ro, const float* __restrict__ W4w,
    const float* __restrict__ W4b, float* __restrict__ out_act,
    float* __restrict__ ws) {
  int t = blockIdx.x, tid = threadIdx.x;
  __shared__ float acS[V];
  const float* ac = out_ac + (size_t)t * V;
  acS[tid] = ac[tid];
  acS[tid + 256] = ac[tid + 256];
  __syncthreads();
  float s0 = 0.f, s1 = 0.f;
  const int w0 = tid, w1 = 256 + tid;
  for (int v = 0; v < V; ++v) {
    float a = acS[v];
    const float* er = emb + (size_t)v * WV;
    s0 += a * er[w0];
    if (tid < WV - 256) s1 += a * er[w1];
  }
  float inv = 1.f / ws_ro[WS_ACSUM + t];
  s0 *= inv; s1 *= inv;
  out_act[(size_t)t * WV + w0] = s0;
  if (tid < WV - 256) out_act[(size_t)t * WV + w1] = s1;
  float p = s0 * W4w[w0] + (tid < WV - 256 ? s1 * W4w[w1] : 0.f);
  __shared__ float red[256];
  red[tid] = p;
  __syncthreads();
  for (int s = 128; s > 0; s >>= 1) {
    if (tid < s) red[tid] += red[tid + s];
    __syncthreads();
  }
  if (tid == 0) ws[WS_SCAL + t] = red[0] + W4b[0];
}

// ---------------------------------------------------------------------------
// Sequential scan: back to 64 blocks x 256 threads (R3 shape, 8 rows/block,
// ev in regs). NO atomic RMWs: per-block slot stores (parity double-buffered)
// + monotonic per-block flag array; pollers wave-read all 64 flags.
// ---------------------------------------------------------------------------
__global__ __launch_bounds__(256) void k_seq(
    const float* __restrict__ ev0, const float* __restrict__ ws,
    float* __restrict__ slotP, float* __restrict__ slotA, int* __restrict__ flags,
    float* __restrict__ att, float* __restrict__ ktb,
    float* __restrict__ out_ep, float* __restrict__ out_se) {
  const int g = blockIdx.x, tid = threadIdx.x;
  const int lane = tid & 63, wv = tid >> 6;
  const int col = tid * 4;
  __shared__ float attnS[8], prevS[8], red[8][4];
  if (tid < 8) prevS[tid] = 0.f;
  float4 ev[8];
#pragma unroll
  for (int r = 0; r < 8; ++r)
    ev[r] = *(const float4*)(ev0 + (size_t)(g * 8 + r) * H + col);
  __syncthreads();
  for (int t = 0; t < S; ++t) {
    const int buf = t & 1;
    // ---- dots ----
    const float4 w4 = *(const float4*)(ws + WS_W2V + (size_t)t * H + col);
    float dp[8];
#pragma unroll
    for (int r = 0; r < 8; ++r) dp[r] = dot4(ev[r], w4);
#pragma unroll
    for (int r = 0; r < 8; ++r) {
#pragma unroll
      for (int m = 32; m > 0; m >>= 1) dp[r] += __shfl_xor(dp[r], m, 64);
    }
    if (lane == 0) {
#pragma unroll
      for (int r = 0; r < 8; ++r) red[r][wv] = dp[r];
    }
    __syncthreads();                      // (a)
    if (tid < 8) {
      float d  = red[tid][0] + red[tid][1] + red[tid][2] + red[tid][3];
      float ep = 1.f / (1.f + __expf(-d));
      out_ep[(size_t)t * N + g * 8 + tid] = ep;
      float a = ws[WS_CHOICE + 2 * t] * ep + ws[WS_CHOICE + 2 * t + 1] * prevS[tid];
      prevS[tid] = ep;
      attnS[tid] = a;
      att[(size_t)t * N + g * 8 + tid] = a;
    }
    __syncthreads();                      // (b)
    float at[8];
#pragma unroll
    for (int r = 0; r < 8; ++r) at[r] = attnS[r];
    float4 pv = make_float4(0.f, 0.f, 0.f, 0.f);
#pragma unroll
    for (int r = 0; r < 8; ++r) {
      pv.x += at[r] * ev[r].x; pv.y += at[r] * ev[r].y;
      pv.z += at[r] * ev[r].z; pv.w += at[r] * ev[r].w;
    }
    float* sp = slotP + (size_t)(buf * 64 + g) * 1024 + col;
    __hip_atomic_store(sp + 0, pv.x, __ATOMIC_RELAXED, __HIP_MEMORY_SCOPE_AGENT);
    __hip_atomic_store(sp + 1, pv.y, __ATOMIC_RELAXED, __HIP_MEMORY_SCOPE_AGENT);
    __hip_atomic_store(sp + 2, pv.z, __ATOMIC_RELAXED, __HIP_MEMORY_SCOPE_AGENT);
    __hip_atomic_store(sp + 3, pv.w, __ATOMIC_RELAXED, __HIP_MEMORY_SCOPE_AGENT);
    if (tid == 0) {
      float pa = 0.f;
#pragma unroll
      for (int r = 0; r < 8; ++r) pa += at[r];
      __hip_atomic_store(slotA + buf * 64 + g, pa, __ATOMIC_RELAXED, __HIP_MEMORY_SCOPE_AGENT);
    }
    // ---- arrival: per-wave drain, then one flag store ----
    __threadfence();
    __syncthreads();
    if (tid == 0)
      __hip_atomic_store(flags + g, t + 1, __ATOMIC_RELAXED, __HIP_MEMORY_SCOPE_AGENT);
    // ---- poll: every wave reads all 64 flags ----
    for (;;) {
      int f = __hip_atomic_load(flags + lane, __ATOMIC_RELAXED, __HIP_MEMORY_SCOPE_AGENT);
      if (__all(f >= t + 1)) break;
    }
    // ---- phase 2: asum via wave-wide load+reduce; bar via 64 slot loads ----
    float av = __hip_atomic_load(slotA + buf * 64 + lane, __ATOMIC_RELAXED, __HIP_MEMORY_SCOPE_AGENT);
#pragma unroll
    for (int m = 32; m > 0; m >>= 1) av += __shfl_xor(av, m, 64);
    float4 bar = make_float4(0.f, 0.f, 0.f, 0.f);
#pragma unroll
    for (int s = 0; s < 64; ++s) {
      const float* q = slotP + (size_t)(buf * 64 + s) * 1024 + col;
      bar.x += __hip_atomic_load(q + 0, __ATOMIC_RELAXED, __HIP_MEMORY_SCOPE_AGENT);
      bar.y += __hip_atomic_load(q + 1, __ATOMIC_RELAXED, __HIP_MEMORY_SCOPE_AGENT);
      bar.z += __hip_atomic_load(q + 2, __ATOMIC_RELAXED, __HIP_MEMORY_SCOPE_AGENT);
      bar.w += __hip_atomic_load(q + 3, __ATOMIC_RELAXED, __HIP_MEMORY_SCOPE_AGENT);
    }
    float inv = 1.f / av;
    bar.x *= inv; bar.y *= inv; bar.z *= inv; bar.w *= inv;
    float sc = ws[WS_SCAL + t];
    float4 kt = make_float4(fmaxf(sc * bar.x, 0.f), fmaxf(sc * bar.y, 0.f),
                            fmaxf(sc * bar.z, 0.f), fmaxf(sc * bar.w, 0.f));
    if (g == 0) {
      *(float4*)(out_se + (size_t)t * H + col) = bar;
      *(float4*)(ktb + (size_t)t * H + col) = kt;
    }
#pragma unroll
    for (int r = 0; r < 8; ++r) {
      float a = at[r];
      ev[r].x = a * kt.x + (1.f - a) * ev[r].x;
      ev[r].y = a * kt.y + (1.f - a) * ev[r].y;
      ev[r].z = a * kt.z + (1.f - a) * ev[r].z;
      ev[r].w = a * kt.w + (1.f - a) * ev[r].w;
    }
  }
}

// Reconstruct out_all[t,n,:] from ev0, attn, kt: per-row affine scan.
__global__ __launch_bounds__(256) void k_recon(
    const float* __restrict__ ev0, const float* __restrict__ att,
    const float* __restrict__ ktb, float* __restrict__ out_all) {
  const int n = blockIdx.x, tid = threadIdx.x;
  const int col = tid * 4;
  __shared__ float aS[S];
  if (tid < S) aS[tid] = att[(size_t)tid * N + n];
  float4 v = *(const float4*)(ev0 + (size_t)n * H + col);
  __syncthreads();
  for (int t = 0; t < S; ++t) {
    float a = aS[t];
    float4 k4 = *(const float4*)(ktb + (size_t)t * H + col);
    v.x = a * k4.x + (1.f - a) * v.x;
    v.y = a * k4.y + (1.f - a) * v.y;
    v.z = a * k4.z + (1.f - a) * v.z;
    v.w = a * k4.w + (1.f - a) * v.w;
    *(float4*)(out_all + ((size_t)t * N + n) * H + col) = v;
  }
}

extern "C" void kernel_launch(void* const* d_in, const int* in_sizes, int n_in,
                              void* d_out, int out_size, void* d_ws, size_t ws_size,
                              hipStream_t stream) {
  const float* vv  = (const float*)d_in[0];
  const float* ev0 = (const float*)d_in[1];
  const float* A1w = (const float*)d_in[2];
  const float* A1b = (const float*)d_in[3];
  const float* A2w = (const float*)d_in[4];
  const float* A2b = (const float*)d_in[5];
  const float* emb = (const float*)d_in[6];
  const float* W1w = (const float*)d_in[7];
  const float* W1b = (const float*)d_in[8];
  const float* W2w = (const float*)d_in[9];
  const float* W2b = (const float*)d_in[10];
  const float* W3w = (const float*)d_in[11];
  const float* W3b = (const float*)d_in[12];
  const float* W4w = (const float*)d_in[13];
  const float* W4b = (const float*)d_in[14];

  float* ws  = (float*)d_ws;
  float* out = (float*)d_out;
  float* out_ep  = out + OUT_EP;
  float* out_ac  = out + OUT_AC;
  float* out_se  = out + OUT_SE;
  float* out_all = out + OUT_ALL;
  float* out_act = out + OUT_ACT;
  float* cat = ws + WS_CAT;
  float* P   = out_all;   // gemm partial scratch; out_all written only by k_recon

  hipMemsetAsync(ws + WS_FLAGS, 0, 64 * sizeof(int), stream);

  // Stage 1: Hall = relu(vv@A1w^T+A1b); hat = relu(vv@W1w^T+W1b) -> cat
  {
    SKArgs a{vv, A1w, W1w, P, H, H, H / KP, H};
    g_split<<<dim3(16, KP, 2), 256, 0, stream>>>(a);
    EPArgs e{P, A1b, W1b, ws + WS_HALL, nullptr, cat, nullptr, 10, H, 0, 1536, 0, 1};
    ep_k<<<dim3(256, 2), 256, 0, stream>>>(e);
  }
  // Stage 2: ac = sigmoid(Hall@A2w^T+A2b) -> out_ac and cat[:,1024:]
  {
    SKArgs a{ws + WS_HALL, A2w, A2w, P, H, H, H / KP, V};
    g_split<<<dim3(8, KP, 1), 256, 0, stream>>>(a);
    EPArgs e{P, A2b, A2b, out_ac, cat + H, nullptr, nullptr, 9, V, 1536, 0, 0, 2};
    ep_k<<<dim3(128, 1), 256, 0, stream>>>(e);
  }
  k_choice<<<S, 256, 0, stream>>>(cat, out_ac, W3w, W3b, ws);
  // Stage 3: w2v = cat@W2w^T + W2b
  {
    SKArgs a{cat, W2w, W2w, P, 1536, 1536, 1536 / KP, H};
    g_split<<<dim3(16, KP, 1), 256, 0, stream>>>(a);
    EPArgs e{P, W2b, W2b, ws + WS_W2V, nullptr, nullptr, nullptr, 10, H, 0, 0, 0, 0};
    ep_k<<<dim3(256, 1), 256, 0, stream>>>(e);
  }
  k_barft<<<S, 256, 0, stream>>>(out_ac, emb, ws, W4w, W4b, out_act, ws);
  k_seq<<<64, 256, 0, stream>>>(ev0, ws, ws + WS_SLOTP, ws + WS_SLOTA,
                                (int*)(ws + WS_FLAGS),
                                ws + WS_ATT, ws + WS_KT, out_ep, out_se);
  k_recon<<<N, 256, 0, stream>>>(ev0, ws + WS_ATT, ws + WS_KT, out_all);
}

// Round 6
// 1579.130 us; speedup vs baseline: 1.1576x; 1.1576x over previous
//
#include <hip/hip_runtime.h>

#define H  1024
#define V  512
#define WV 300
#define S  64
#define N  512

// ---- workspace float offsets ----
#define WS_HALL   0                         // [S,H]
#define WS_CAT    (S*H)                     // [S,1536]  (hat | ac)
#define WS_W2V    (WS_CAT + S*1536)         // [S,H]
#define WS_CHOICE (WS_W2V + S*H)            // [S,2]
#define WS_SCAL   (WS_CHOICE + 2*S)         // [S]
#define WS_ACSUM  (WS_SCAL + S)             // [S]
#define WS_KT     (WS_ACSUM + S)            // [S,H]
#define WS_ATT    (WS_KT + S*H)             // [S,N]
#define WS_D0     (WS_ATT + S*N)            // [N,S]
#define WS_APUB   (WS_D0 + N*S)             // [2][512]
#define WS_GP1    (WS_APUB + 1024)          // [2][64]
#define WS_GBIG   (WS_GP1 + 128)            // [2][64][64]
#define WS_FLAGA  (WS_GBIG + 8192)          // [64]
#define WS_FLAGB  (WS_FLAGA + 64)           // [64]
#define WS_FLAGD  (WS_FLAGB + 64)           // [64]

// ---- out float offsets ----
#define OUT_EP   0                  // [S,N]
#define OUT_AC   (S*N)              // [S,V]
#define OUT_SE   (S*N + S*V)        // [S,H]
#define OUT_ALL  (OUT_SE + S*H)     // [S,N,H]
#define OUT_ACT  (OUT_ALL + (size_t)S*N*H) // [S,WV]

#define RLX __ATOMIC_RELAXED
#define AGT __HIP_MEMORY_SCOPE_AGENT

__device__ __forceinline__ float dot4(float4 a, float4 b) {
  return a.x*b.x + a.y*b.y + a.z*b.z + a.w*b.w;
}
__device__ __forceinline__ float wave_reduce(float v) {
#pragma unroll
  for (int m = 32; m > 0; m >>= 1) v += __shfl_xor(v, m, 64);
  return v;
}

// Hall = relu(vv@A1w^T+A1b); hat = relu(vv@W1w^T+W1b) -> cat[:, :1024].
// One wave per output, j-major so 64 consecutive waves reuse one weight row.
__global__ void k_vvmats(const float* __restrict__ vv,
                         const float* __restrict__ A1w, const float* __restrict__ A1b,
                         const float* __restrict__ W1w, const float* __restrict__ W1b,
                         float* __restrict__ ws) {
  int wid  = (blockIdx.x * 256 + threadIdx.x) >> 6;
  int lane = threadIdx.x & 63;
  int mat = wid >= H * S;
  int rem = wid - mat * H * S;
  int j = rem >> 6, t = rem & 63;
  const float* w = (mat ? W1w : A1w) + (size_t)j * H;
  const float* x = vv + (size_t)t * H;
  float s = 0.f;
#pragma unroll
  for (int c = 0; c < 4; ++c)
    s += dot4(*(const float4*)(w + c*256 + lane*4), *(const float4*)(x + c*256 + lane*4));
  s = wave_reduce(s);
  if (lane == 0) {
    s = fmaxf(s + (mat ? W1b : A1b)[j], 0.f);
    if (mat) ws[WS_CAT + (size_t)t * 1536 + j] = s;
    else     ws[WS_HALL + (size_t)t * H + j] = s;
  }
}

// ac = sigmoid(Hall@A2w^T+A2b) -> out_ac and cat[:,1024:]. One wave/output, v-major.
__global__ void k_ac(const float* __restrict__ ws_ro, const float* __restrict__ A2w,
                     const float* __restrict__ A2b, float* __restrict__ out_ac,
                     float* __restrict__ ws) {
  int wid  = (blockIdx.x * 256 + threadIdx.x) >> 6;
  int lane = threadIdx.x & 63;
  int v = wid >> 6, t = wid & 63;
  const float* x = ws_ro + WS_HALL + (size_t)t * H;
  const float* w = A2w + (size_t)v * H;
  float s = 0.f;
#pragma unroll
  for (int c = 0; c < 4; ++c)
    s += dot4(*(const float4*)(w + c*256 + lane*4), *(const float4*)(x + c*256 + lane*4));
  s = wave_reduce(s);
  if (lane == 0) {
    s = 1.f / (1.f + __expf(-(s + A2b[v])));
    out_ac[(size_t)t * V + v] = s;
    ws[WS_CAT + (size_t)t * 1536 + H + v] = s;
  }
}

// w2v = cat@W2w^T + W2b. One wave per output, j-major.
__global__ void k_w2v(const float* __restrict__ ws_ro, const float* __restrict__ W2w,
                      const float* __restrict__ W2b, float* __restrict__ ws) {
  int wid  = (blockIdx.x * 256 + threadIdx.x) >> 6;
  int lane = threadIdx.x & 63;
  int j = wid >> 6, t = wid & 63;
  const float* x = ws_ro + WS_CAT + (size_t)t * 1536;
  const float* w = W2w + (size_t)j * 1536;
  float s = 0.f;
#pragma unroll
  for (int c = 0; c < 6; ++c)
    s += dot4(*(const float4*)(w + c*256 + lane*4), *(const float4*)(x + c*256 + lane*4));
  s = wave_reduce(s);
  if (lane == 0) ws[WS_W2V + (size_t)t * H + j] = s + W2b[j];
}

// D0[n,t] = ev0[n]·w2v_t. One wave per output, n-major.
__global__ void k_d0(const float* __restrict__ ev0, const float* __restrict__ ws_ro,
                     float* __restrict__ D0out) {
  int wid  = (blockIdx.x * 256 + threadIdx.x) >> 6;
  int lane = threadIdx.x & 63;
  int n = wid >> 6, t = wid & 63;
  const float* x = ev0 + (size_t)n * H;
  const float* w = ws_ro + WS_W2V + (size_t)t * H;
  float s = 0.f;
#pragma unroll
  for (int c = 0; c < 4; ++c)
    s += dot4(*(const float4*)(x + c*256 + lane*4), *(const float4*)(w + c*256 + lane*4));
  s = wave_reduce(s);
  if (lane == 0) D0out[wid] = s;
}

// choice softmax (c0,c1) and acsum. hat read from cat (stride 1536).
__global__ void k_choice(const float* __restrict__ cat, const float* __restrict__ out_ac,
                         const float* __restrict__ W3w, const float* __restrict__ W3b,
                         float* __restrict__ ws) {
  int t = blockIdx.x, tid = threadIdx.x;
  const float* hat = cat + (size_t)t * 1536;
  float4 h4 = *(const float4*)(hat + tid * 4);
  float p[4];
#pragma unroll
  for (int r = 0; r < 3; ++r)
    p[r] = dot4(h4, *(const float4*)(W3w + (size_t)r * H + tid * 4));
  const float* ac = out_ac + (size_t)t * V;
  p[3] = ac[tid * 2] + ac[tid * 2 + 1];
  __shared__ float red[4][256];
#pragma unroll
  for (int q = 0; q < 4; ++q) red[q][tid] = p[q];
  __syncthreads();
  for (int sft = 128; sft > 0; sft >>= 1) {
    if (tid < sft) {
#pragma unroll
      for (int q = 0; q < 4; ++q) red[q][tid] += red[q][tid + sft];
    }
    __syncthreads();
  }
  if (tid == 0) {
    float l0 = red[0][0] + W3b[0], l1 = red[1][0] + W3b[1], l2 = red[2][0] + W3b[2];
    float m  = fmaxf(l0, fmaxf(l1, l2));
    float e0 = __expf(l0 - m), e1 = __expf(l1 - m), e2 = __expf(l2 - m);
    float inv = 1.f / (e0 + e1 + e2);
    ws[WS_CHOICE + t * 2]     = e0 * inv;
    ws[WS_CHOICE + t * 2 + 1] = e1 * inv;
    ws[WS_ACSUM + t]          = red[3][0];
  }
}

// bar_ft = (ac/acsum)@emb -> out_act, plus scal = bar_ft@W4w + W4b (folded).
__global__ __launch_bounds__(256) void k_barft(
    const float* __restrict__ out_ac, const float* __restrict__ emb,
    const float* __restrict__ ws_ro, const float* __restrict__ W4w,
    const float* __restrict__ W4b, float* __restrict__ out_act,
    float* __restrict__ ws) {
  int t = blockIdx.x, tid = threadIdx.x;
  __shared__ float acS[V];
  const float* ac = out_ac + (size_t)t * V;
  acS[tid] = ac[tid];
  acS[tid + 256] = ac[tid + 256];
  __syncthreads();
  float s0 = 0.f, s1 = 0.f;
  const int w0 = tid, w1 = 256 + tid;
  for (int v = 0; v < V; ++v) {
    float a = acS[v];
    const float* er = emb + (size_t)v * WV;
    s0 += a * er[w0];
    if (tid < WV - 256) s1 += a * er[w1];
  }
  float inv = 1.f / ws_ro[WS_ACSUM + t];
  s0 *= inv; s1 *= inv;
  out_act[(size_t)t * WV + w0] = s0;
  if (tid < WV - 256) out_act[(size_t)t * WV + w1] = s1;
  float p = s0 * W4w[w0] + (tid < WV - 256 ? s1 * W4w[w1] : 0.f);
  __shared__ float red[256];
  red[tid] = p;
  __syncthreads();
  for (int s = 128; s > 0; s >>= 1) {
    if (tid < s) red[tid] += red[tid + s];
    __syncthreads();
  }
  if (tid == 0) ws[WS_SCAL + t] = red[0] + W4b[0];
}

// ---------------------------------------------------------------------------
// Sequential scan via the dot-recurrence D_t[n,t'] = a_t G[t,t'] + (1-a_t) D.
// 64 blocks x 256 threads. Block g owns: n-slice g*8..+7 (D state in LDS) AND
// col-slice g*16..+15 (ev columns in registers, 32/thread). Critical path per
// step: publish a (2KB) -> local bar/kt -> publish 1 G-scalar partial ->
// update D[:,t+1]. Far-future G row + D catch-up + ev update have 1 step slack.
// ---------------------------------------------------------------------------
__global__ __launch_bounds__(256) void k_seq(
    const float* __restrict__ ev0, const float* __restrict__ ws,
    const float* __restrict__ D0,
    float* __restrict__ aPub, float* __restrict__ gp1, float* __restrict__ gbig,
    int* __restrict__ flagA, int* __restrict__ flagB, int* __restrict__ flagD,
    float* __restrict__ att, float* __restrict__ ktb,
    float* __restrict__ out_ep, float* __restrict__ out_se) {
  const int g = blockIdx.x, tid = threadIdx.x;
  const int lane = tid & 63;
  const int cg = tid & 15, ng = tid >> 4;
  const int colbase = g * 16;
  __shared__ float Dl[8][64];
  __shared__ float aL[512];
  __shared__ float red2[16][17];
  __shared__ alignas(16) float ktL[16];
  __shared__ float attnS[8], aOldS[8], prevS[8];
  __shared__ float Grow[64];
  __shared__ float asumS;
  for (int i = tid; i < 512; i += 256)
    Dl[i >> 6][i & 63] = D0[(size_t)(g * 8 + (i >> 6)) * 64 + (i & 63)];
  if (tid < 8) { prevS[tid] = 0.f; attnS[tid] = 0.f; }
  float evr[32];
#pragma unroll
  for (int i = 0; i < 32; ++i)
    evr[i] = ev0[(size_t)(ng * 32 + i) * H + colbase + cg];
  __syncthreads();

  for (int t = 0; t < S; ++t) {
    const int buf = t & 1;
    // ---------- phase A: a_t from D[n,t]; publish ----------
    if (tid < 8) {
      float d  = Dl[tid][t];
      float ep = 1.f / (1.f + __expf(-d));
      out_ep[(size_t)t * N + g * 8 + tid] = ep;
      float a = ws[WS_CHOICE + 2*t] * ep + ws[WS_CHOICE + 2*t + 1] * prevS[tid];
      prevS[tid] = ep;
      aOldS[tid] = attnS[tid];          // save a_{t-1} for phase E
      attnS[tid] = a;
      att[(size_t)t * N + g * 8 + tid] = a;
      __hip_atomic_store(aPub + buf * 512 + g * 8 + tid, a, RLX, AGT);
    }
    __threadfence();
    __syncthreads();
    if (tid == 0) __hip_atomic_store(flagA + g, t + 1, RLX, AGT);

    // ---------- phase E: apply s=t-1 to slices t'>=t+1 (off critical) ------
    if (t >= 1 && t < 63) {
      const int pbuf = (t + 1) & 1;
      if (tid < 64) {
        for (;;) {
          int f = __hip_atomic_load(flagD + lane, RLX, AGT);
          if (__all(f >= t)) break;
        }
      }
      __syncthreads();
      int row = t + 1 + (tid >> 2);
      float rs = 0.f;
      if (row < 64) {
        const float* p = gbig + ((size_t)pbuf * 64 + row) * 64 + (tid & 3) * 16;
#pragma unroll
        for (int i = 0; i < 16; ++i) rs += __hip_atomic_load(p + i, RLX, AGT);
      }
      rs += __shfl_xor(rs, 1, 64);
      rs += __shfl_xor(rs, 2, 64);
      if ((tid & 3) == 0 && row < 64) Grow[row] = rs;
      __syncthreads();
      {
        int n = tid >> 5;
        float ao = aOldS[n];
        for (int r = (tid & 31) + t + 1; r < 64; r += 32)
          Dl[n][r] = ao * Grow[r] + (1.f - ao) * Dl[n][r];
      }
      __syncthreads();
    }

    // ---------- phase B: col role — bar, kt, ev update ----------
    if (tid < 64) {
      for (;;) {
        int f = __hip_atomic_load(flagA + lane, RLX, AGT);
        if (__all(f >= t + 1)) break;
      }
    }
    __syncthreads();
    aL[tid]       = __hip_atomic_load(aPub + buf * 512 + tid, RLX, AGT);
    aL[tid + 256] = __hip_atomic_load(aPub + buf * 512 + 256 + tid, RLX, AGT);
    __syncthreads();
    if (tid < 64) {
      float s = 0.f;
      for (int i = lane; i < 512; i += 64) s += aL[i];
      s = wave_reduce(s);
      if (tid == 0) asumS = s;
    }
    float bp = 0.f;
#pragma unroll
    for (int i = 0; i < 32; ++i) bp += aL[ng * 32 + i] * evr[i];
    red2[ng][cg] = bp;
    __syncthreads();
    if (tid < 16) {
      float b = 0.f;
#pragma unroll
      for (int q = 0; q < 16; ++q) b += red2[q][tid];
      b /= asumS;
      float sc = ws[WS_SCAL + t];
      float k  = fmaxf(sc * b, 0.f);
      ktL[tid] = k;
      out_se[(size_t)t * H + colbase + tid] = b;
      ktb[(size_t)t * H + colbase + tid]    = k;
    }
    __syncthreads();
    if (t < 63) {
      if (tid < 16)
        red2[0][tid] = ktL[tid] * ws[WS_W2V + (size_t)(t + 1) * H + colbase + tid];
      __syncthreads();
      if (tid == 0) {
        float s = 0.f;
#pragma unroll
        for (int q = 0; q < 16; ++q) s += red2[0][q];
        __hip_atomic_store(gp1 + buf * 64 + g, s, RLX, AGT);
      }
    }
    {
      float k = ktL[cg];
#pragma unroll
      for (int i = 0; i < 32; ++i) {
        float a = aL[ng * 32 + i];
        evr[i] = a * k + (1.f - a) * evr[i];
      }
    }
    __threadfence();
    __syncthreads();
    if (tid == 0) __hip_atomic_store(flagB + g, t + 1, RLX, AGT);

    // ---------- phase C: G[t,t+1] -> D[:,t+1] ----------
    if (t < 63) {
      if (tid < 64) {
        for (;;) {
          int f = __hip_atomic_load(flagB + lane, RLX, AGT);
          if (__all(f >= t + 1)) break;
        }
      }
      __syncthreads();
      if (tid < 64) {
        float v = __hip_atomic_load(gp1 + buf * 64 + lane, RLX, AGT);
        v = wave_reduce(v);
        if (tid == 0) Grow[0] = v;
      }
      __syncthreads();
      if (tid < 8) {
        float a = attnS[tid];
        Dl[tid][t + 1] = a * Grow[0] + (1.f - a) * Dl[tid][t + 1];
      }
    }

    // ---------- phase D: far-future G partials (1 step slack) ----------
    if (t < 62) {
      int tp = t + 2 + (tid >> 2);
      if (tp < 64) {
        float4 w4 = *(const float4*)(ws + WS_W2V + (size_t)tp * H + colbase + (tid & 3) * 4);
        float4 k4 = *(const float4*)&ktL[(tid & 3) * 4];
        float s = dot4(w4, k4);
        s += __shfl_xor(s, 1, 64);
        s += __shfl_xor(s, 2, 64);
        if ((tid & 3) == 0)
          __hip_atomic_store(gbig + ((size_t)buf * 64 + tp) * 64 + g, s, RLX, AGT);
      }
    }
    __threadfence();
    __syncthreads();
    if (tid == 0) __hip_atomic_store(flagD + g, t + 1, RLX, AGT);
  }
}

// Reconstruct out_all[t,n,:] from ev0, attn, kt: per-row affine scan.
__global__ __launch_bounds__(256) void k_recon(
    const float* __restrict__ ev0, const float* __restrict__ att,
    const float* __restrict__ ktb, float* __restrict__ out_all) {
  const int n = blockIdx.x, tid = threadIdx.x;
  const int col = tid * 4;
  __shared__ float aS[S];
  if (tid < S) aS[tid] = att[(size_t)tid * N + n];
  float4 v = *(const float4*)(ev0 + (size_t)n * H + col);
  __syncthreads();
  for (int t = 0; t < S; ++t) {
    float a = aS[t];
    float4 k4 = *(const float4*)(ktb + (size_t)t * H + col);
    v.x = a * k4.x + (1.f - a) * v.x;
    v.y = a * k4.y + (1.f - a) * v.y;
    v.z = a * k4.z + (1.f - a) * v.z;
    v.w = a * k4.w + (1.f - a) * v.w;
    *(float4*)(out_all + ((size_t)t * N + n) * H + col) = v;
  }
}

extern "C" void kernel_launch(void* const* d_in, const int* in_sizes, int n_in,
                              void* d_out, int out_size, void* d_ws, size_t ws_size,
                              hipStream_t stream) {
  const float* vv  = (const float*)d_in[0];
  const float* ev0 = (const float*)d_in[1];
  const float* A1w = (const float*)d_in[2];
  const float* A1b = (const float*)d_in[3];
  const float* A2w = (const float*)d_in[4];
  const float* A2b = (const float*)d_in[5];
  const float* emb = (const float*)d_in[6];
  const float* W1w = (const float*)d_in[7];
  const float* W1b = (const float*)d_in[8];
  const float* W2w = (const float*)d_in[9];
  const float* W2b = (const float*)d_in[10];
  const float* W3w = (const float*)d_in[11];
  const float* W3b = (const float*)d_in[12];
  const float* W4w = (const float*)d_in[13];
  const float* W4b = (const float*)d_in[14];

  float* ws  = (float*)d_ws;
  float* out = (float*)d_out;
  float* out_ep  = out + OUT_EP;
  float* out_ac  = out + OUT_AC;
  float* out_se  = out + OUT_SE;
  float* out_all = out + OUT_ALL;
  float* out_act = out + OUT_ACT;
  float* cat = ws + WS_CAT;

  hipMemsetAsync(ws + WS_FLAGA, 0, 192 * sizeof(int), stream);

  k_vvmats<<<(2 * H * S) / 4, 256, 0, stream>>>(vv, A1w, A1b, W1w, W1b, ws);
  k_ac    <<<(V * S) / 4,     256, 0, stream>>>(ws, A2w, A2b, out_ac, ws);
  k_choice<<<S,               256, 0, stream>>>(cat, out_ac, W3w, W3b, ws);
  k_w2v   <<<(H * S) / 4,     256, 0, stream>>>(ws, W2w, W2b, ws);
  k_d0    <<<(N * S) / 4,     256, 0, stream>>>(ev0, ws, ws + WS_D0);
  k_barft <<<S,               256, 0, stream>>>(out_ac, emb, ws, W4w, W4b, out_act, ws);
  k_seq   <<<64,              256, 0, stream>>>(ev0, ws, ws + WS_D0,
                                                ws + WS_APUB, ws + WS_GP1, ws + WS_GBIG,
                                                (int*)(ws + WS_FLAGA), (int*)(ws + WS_FLAGB),
                                                (int*)(ws + WS_FLAGD),
                                                ws + WS_ATT, ws + WS_KT, out_ep, out_se);
  k_recon <<<N,               256, 0, stream>>>(ev0, ws + WS_ATT, ws + WS_KT, out_all);
}